// Round 16
// baseline (193.056 us; speedup 1.0000x reference)
//
#include <hip/hip_runtime.h>
#include <math.h>

// Problem constants (match reference)
#define BB 8
#define AA 512
#define NBH 64
#define FF 128
#define GG 50
#define CUTOFF 5.0f

typedef __attribute__((ext_vector_type(8)))  short bf16x8;   // 8 bf16 = 4 VGPRs
typedef __attribute__((ext_vector_type(4)))  float f32x4;    // 16x16 MFMA C/D
typedef __attribute__((ext_vector_type(16))) float f32x16;   // 32x32 MFMA C/D

#define MST 136   // M_s row stride (shorts); with XOR swizzle reads/writes are conflict-light

// ws layout (bf16 elems)
#define WV_OFF   0                      // Wv packed, 32-col B-frag (8 steps of 16)
#define WO_OFF   16384                  // Wo packed, 16-col B-frag (4 steps of 32)
#define WF_OFF   32768                  // W_filt packed, 32-col, K-pad; row 50 = b_filt
#define KQ_OFF   40960                  // kqc[atom][head][i] bf16, 0.25-scaled (8 MB)
#define PACK_ELEMS 40960
#define PACK_BLOCKS (PACK_ELEMS / 256)  // 160
#define QK_BLOCKS  1024                 // 4 waves/block, 1 atom per wave

// RNE
__device__ __forceinline__ short f2bf(float f) {
    union { float f; unsigned u; } v; v.f = f;
    unsigned r = v.u + 0x7fffu + ((v.u >> 16) & 1u);
    return (short)(r >> 16);
}
// fast round-half-up (2 VALU)
__device__ __forceinline__ short f2bf_fast(float f) {
    return (short)((__float_as_uint(f) + 0x8000u) >> 16);
}
// pack 2 floats -> 2 bf16 in one dword: 2 adds + 1 v_perm
__device__ __forceinline__ unsigned int pk2bf(float a, float b) {
    unsigned int ua = __float_as_uint(a) + 0x8000u;
    unsigned int ub = __float_as_uint(b) + 0x8000u;
    return __builtin_amdgcn_perm(ub, ua, 0x07060302u);
}
// Load 8 consecutive floats (8B-aligned) from global -> bf16x8 A-fragment (packed cvt)
__device__ __forceinline__ bf16x8 ld_f8_bfpk(const float* p) {
    const float2* p2 = (const float2*)p;
    float2 a = p2[0], b = p2[1], c = p2[2], d = p2[3];
    union { unsigned int u[4]; bf16x8 v; } r;
    r.u[0] = pk2bf(a.x, a.y);
    r.u[1] = pk2bf(b.x, b.y);
    r.u[2] = pk2bf(c.x, c.y);
    r.u[3] = pk2bf(d.x, d.y);
    return r.v;
}
__device__ __forceinline__ int swz(int n) { return ((n >> 3) & 3) << 3; }  // LDS k-index XOR swizzle

// ---------------- launch 1: pack weights (160 blocks) + qk per atom (1024 blocks) ---
// Single launch, no dependency: qk blocks read only RAW fp32 inputs (Wq, Wk, x).
// Pack layouts:
//   32-col (Wv/Wf): dst[((w*S+s)*64+l)*8+j] = W[16s + (l>>5)*8 + j][32w + (l&31)]
//   16-col (Wo):    dst[((c*4+s)*64+l)*8+j] = W[32s + (l>>4)*8 + j][16c + (l&15)]
//   Wf K-pad rows 50..63: row 50 carries b_filt (A supplies 1.0 there), 51..63 zero.
// qk (R14's VALU version cost ~55us; R15's MFMA version ~8us; this folds it into
// pack's launch): q = broadcast-A(x).B(Wq scalar-built) (32 MFMAs, 0.25-scaled);
// KQ = Qmask . Wk^T: A'[m=head][k] = q[k]*(k>>4==m); B fragments are contiguous
// Wk rows (ld_f8_bfpk). D rows 0..7 = kq[head][:].
__global__ void prep_kernel(const float* __restrict__ Wk,
                            const float* __restrict__ Wv,
                            const float* __restrict__ Wq,
                            const float* __restrict__ Wo,
                            const float* __restrict__ Wf,
                            const float* __restrict__ b_filt,
                            const float* __restrict__ x,
                            short* __restrict__ ws)
{
    const int bid = blockIdx.x;
    const int tid = threadIdx.x;

    __shared__ short qls[4][128];             // per-wave q, bf16, 0.25-scaled

    if (bid < PACK_BLOCKS) {
        int gid = bid * 256 + tid;
        if (gid < 16384) {                    // Wv, 32-col layout
            int idx = gid;
            int j = idx & 7, l = (idx >> 3) & 63, rest = idx >> 9;
            int s = rest & 7, w = rest >> 3;
            int k = 16 * s + ((l >> 5) << 3) + j;
            int n = 32 * w + (l & 31);
            ws[WV_OFF + idx] = f2bf(Wv[k * FF + n]);
        } else if (gid < 32768) {             // Wo, 16-col layout
            int idx = gid - 16384;
            int j = idx & 7, l = (idx >> 3) & 63, rest = idx >> 9;
            int s = rest & 3, c = rest >> 2;
            int k = 32 * s + (l >> 4) * 8 + j;
            int n = 16 * c + (l & 15);
            ws[WO_OFF + idx] = f2bf(Wo[k * FF + n]);
        } else {                              // Wf, 32-col, K-pad, bias row 50
            int idx = gid - 32768;
            int j = idx & 7, l = (idx >> 3) & 63, rest = idx >> 9;
            int s = rest & 3, w = rest >> 2;
            int k = 16 * s + ((l >> 5) << 3) + j;
            int n = 32 * w + (l & 31);
            float v = (k < GG) ? Wf[k * FF + n] : (k == GG ? b_filt[n] : 0.0f);
            ws[WF_OFF + idx] = f2bf(v);
        }
        return;
    }

    // ---- qk blocks: 4 waves, one atom per wave ----
    const int w    = tid >> 6;
    const int lane = tid & 63;
    const int a    = (bid - PACK_BLOCKS) * 4 + w;    // 0..4095
    const int l15  = lane & 15;
    const int quad = lane >> 4;

    // q via broadcast-A MFMA; B fragments built from raw Wq (8 strided L2-hot loads)
    {
        bf16x8 xa[4];
#pragma unroll
        for (int s = 0; s < 4; ++s)
            xa[s] = ld_f8_bfpk(x + (size_t)a * FF + 32 * s + quad * 8);
#pragma unroll
        for (int cg = 0; cg < 8; ++cg) {
            f32x4 z = {0.f, 0.f, 0.f, 0.f};
#pragma unroll
            for (int s = 0; s < 4; ++s) {
                const float* wq = Wq + (size_t)(32 * s + quad * 8) * FF + 16 * cg + l15;
                bf16x8 bq;
#pragma unroll
                for (int j = 0; j < 8; ++j) bq[j] = f2bf_fast(wq[j * FF]);
                z = __builtin_amdgcn_mfma_f32_16x16x32_bf16(xa[s], bq, z, 0, 0, 0);
            }
            if (quad == 0) qls[w][cg * 16 + l15] = f2bf_fast(z[0] * 0.25f);
        }
    }
    __syncthreads();

    // KQ = A' . Wk^T ; A' fragment for k-octet (s,quad) lies wholly in head 2s+(quad>>1)
    {
        short* kqa = ws + KQ_OFF + (size_t)a * 1024;
        bf16x8 zero8;
#pragma unroll
        for (int jj = 0; jj < 8; ++jj) zero8[jj] = 0;
        bf16x8 ap[4];
#pragma unroll
        for (int s = 0; s < 4; ++s) {
            bf16x8 qoct = *(const bf16x8*)&qls[w][32 * s + quad * 8];
            int h8 = 2 * s + (quad >> 1);
            ap[s] = (l15 == h8) ? qoct : zero8;
        }
#pragma unroll
        for (int ct = 0; ct < 8; ++ct) {
            f32x4 z = {0.f, 0.f, 0.f, 0.f};
#pragma unroll
            for (int s = 0; s < 4; ++s) {
                // B[k][n] = Wk^T[k][16ct+l15] = Wk[16ct+l15][32s+quad*8+j] — contiguous
                bf16x8 bk = ld_f8_bfpk(Wk + (size_t)(16 * ct + l15) * FF + 32 * s + quad * 8);
                z = __builtin_amdgcn_mfma_f32_16x16x32_bf16(ap[s], bk, z, 0, 0, 0);
            }
            if (quad < 2) {                    // D rows 0..7 hold heads
#pragma unroll
                for (int r = 0; r < 4; ++r) {
                    int h = quad * 4 + r;
                    kqa[h * 128 + ct * 16 + l15] = f2bf_fast(z[r]);
                }
            }
        }
    }
}

// ---------------- launch 2: main — one block per atom, 4 waves, 2 barriers ----------
// Wave w owns cols [32w, 32w+32) == heads {2w, 2w+1}, all 64 neighbors.
// 32x32x16 layouts: A[m=lane&31][k=(lane>>5)*8+j]  B[k][n=lane&31]
//                   D: col=lane&31, row=(reg&3)+8*(reg>>2)+4*(lane>>5)
// Phase 2: B cols carry kq[head(col)] (precomputed) -> score MFMA lands
// score(n, lane's head) directly in C-layout; no cross-lane reduction.
// Softmax max-free (scores bounded; masked -> e=0), one final 1/sum.
// launch_bounds min-waves=4 (128-reg cap): 6 forced catastrophic spill (R6).
__global__ __launch_bounds__(256, 4)
void tdt_main(const float* __restrict__ x,
              const float* __restrict__ r_ij,
              const float* __restrict__ f_ij,
              const float* __restrict__ bo,
              const int*   __restrict__ neighbors,
              const int*   __restrict__ nmask,
              const short* __restrict__ WvB,
              const short* __restrict__ WoB,
              const short* __restrict__ WfB,
              const short* __restrict__ kqc,
              float* __restrict__ out)
{
    const int ba   = blockIdx.x;          // 0..4095
    const int b    = ba >> 9;
    const int tid  = threadIdx.x;
    const int lane = tid & 63;
    const int w    = tid >> 6;            // wave 0..3
    const int l15  = lane & 15;
    const int quad = lane >> 4;
    const int l31  = lane & 31;
    const int khalf = (lane >> 5) << 3;   // 0 or 8
    const int w5_4  = (lane >> 5) * 4;

    __shared__ short M_s[NBH * MST];      // modulated messages, swizzled (17.4 KB)
    __shared__ short msg_bf[FF];

    const float* xrow = x + (size_t)ba * FF;   // residual (fp32)
    const float* xb   = x + (size_t)b * AA * FF;
    const size_t bao  = (size_t)ba;

    // per-lane neighbor metadata in REGISTERS:
    int   nbr_reg = neighbors[bao * NBH + lane];
    float C_reg;
    {
        float r = r_ij[bao * NBH + lane];
        float c = 0.5f * (__cosf((float)M_PI * r * (1.0f / CUTOFF)) + 1.0f);
        C_reg = (r < CUTOFF) ? c : 0.0f;
    }
    unsigned long long mask64 = __ballot(nmask[bao * NBH + lane] != 0);

    // ---------------- phase 1: filter 32x32x16 MFMA (A from global f_ij), mt-split --
    {
        const float* fm0 = f_ij + bao * (size_t)(NBH * GG) + (size_t)l31 * GG;
        int c = 32 * w + l31;
#pragma unroll
        for (int mt = 0; mt < 2; ++mt) {
            f32x16 wacc;
#pragma unroll
            for (int r = 0; r < 16; ++r) wacc[r] = 0.0f;
            const float* fm = fm0 + mt * 32 * GG;
#pragma unroll
            for (int s = 0; s < 4; ++s) {
                bf16x8 bfw = *(const bf16x8*)&WfB[((w * 4 + s) * 64 + lane) * 8];
                bf16x8 fa;
                if (s < 3) {
                    fa = ld_f8_bfpk(fm + 16 * s + khalf);
                } else {
                    // k = 48 + khalf + j; k<50 real data, k==50 bias row (A=1.0)
#pragma unroll
                    for (int jj = 0; jj < 8; ++jj) fa[jj] = 0;
                    if (lane < 32) {
                        fa[0] = f2bf_fast(fm[48]);
                        fa[1] = f2bf_fast(fm[49]);
                        fa[2] = (short)0x3F80;   // 1.0bf16 -> adds b_filt row
                    }
                }
                wacc = __builtin_amdgcn_mfma_f32_32x32x16_bf16(fa, bfw, wacc, 0, 0, 0);
            }
            // modulate + gather (fp32 x, 128B coalesced segments) + write M_s
#pragma unroll
            for (int r = 0; r < 16; ++r) {
                int   n   = 32 * mt + (r & 3) + 8 * (r >> 2) + w5_4;
                int   nbn = __shfl(nbr_reg, n, 64);
                float cn  = __shfl(C_reg, n, 64);
                float xv  = xb[(size_t)nbn * FF + c];
                M_s[n * MST + (c ^ swz(n))] = f2bf_fast(wacc[r] * cn * xv);
            }
        }
    }
    __syncthreads();   // M_s ready

    // ---------------- phase 2: score MFMA (B=kq) + v MFMA + max-free softmax --------
    float sum = 0.0f, acc = 0.0f;
    const short* kqa = kqc + (size_t)ba * 1024 + (size_t)(2 * w + ((lane >> 4) & 1)) * 128;
#pragma unroll
    for (int mt = 0; mt < 2; ++mt) {
        int m = 32 * mt + l31;
        f32x16 sacc, vacc;
#pragma unroll
        for (int r = 0; r < 16; ++r) { sacc[r] = 0.0f; vacc[r] = 0.0f; }
#pragma unroll
        for (int s = 0; s < 8; ++s) {
            bf16x8 ma = *(const bf16x8*)&M_s[m * MST + ((16 * s + khalf) ^ swz(m))];
            bf16x8 bq = *(const bf16x8*)&kqa[16 * s + khalf];   // L2-hot, quad-broadcast
            bf16x8 bv = *(const bf16x8*)&WvB[((w * 8 + s) * 64 + lane) * 8];
            sacc = __builtin_amdgcn_mfma_f32_32x32x16_bf16(ma, bq, sacc, 0, 0, 0);
            vacc = __builtin_amdgcn_mfma_f32_32x32x16_bf16(ma, bv, vacc, 0, 0, 0);
        }
#pragma unroll
        for (int r = 0; r < 16; ++r) {
            int   n = 32 * mt + (r & 3) + 8 * (r >> 2) + w5_4;
            float e = ((mask64 >> n) & 1ull) ? __expf(sacc[r]) : 0.0f;
            sum += e;
            acc  = fmaf(e, vacc[r], acc);
        }
    }
    sum += __shfl_xor(sum, 32, 64);                    // other 32 neighbors
    acc += __shfl_xor(acc, 32, 64);
    if (lane < 32) msg_bf[32 * w + l31] = f2bf_fast(acc / sum);
    __syncthreads();   // msg_bf ready

    // ---------------- phase 3: out = msg.Wo + x + bo (16x16x32, broadcast-A) --------
    {
        bf16x8 mga[4];
#pragma unroll
        for (int s = 0; s < 4; ++s)
            mga[s] = *(const bf16x8*)&msg_bf[s * 32 + quad * 8];
#pragma unroll
        for (int ct = 0; ct < 2; ++ct) {
            int cg = 2 * w + ct;
            f32x4 z = {0.f, 0.f, 0.f, 0.f};
#pragma unroll
            for (int s = 0; s < 4; ++s) {
                bf16x8 bw = *(const bf16x8*)&WoB[((cg * 4 + s) * 64 + lane) * 8];
                z = __builtin_amdgcn_mfma_f32_16x16x32_bf16(mga[s], bw, z, 0, 0, 0);
            }
            if (quad == 0) {
                int col = cg * 16 + l15;
                out[bao * FF + col] = z[0] + xrow[col] + bo[col];
            }
        }
    }
}

extern "C" void kernel_launch(void* const* d_in, const int* in_sizes, int n_in,
                              void* d_out, int out_size, void* d_ws, size_t ws_size,
                              hipStream_t stream) {
    // 0:e 1:x 2:t 3:r_ij 4:f_ij 5:W_filt 6:b_filt 7:Wq 8:Wk 9:Wv 10:Wo 11:bo
    // 12:neighbors 13:neighbor_mask (bool -> int32)
    const float* x      = (const float*)d_in[1];
    const float* r_ij   = (const float*)d_in[3];
    const float* f_ij   = (const float*)d_in[4];
    const float* W_filt = (const float*)d_in[5];
    const float* b_filt = (const float*)d_in[6];
    const float* Wq     = (const float*)d_in[7];
    const float* Wk     = (const float*)d_in[8];
    const float* Wv     = (const float*)d_in[9];
    const float* Wo     = (const float*)d_in[10];
    const float* bo     = (const float*)d_in[11];
    const int*   nbr    = (const int*)d_in[12];
    const int*   msk    = (const int*)d_in[13];
    float* out = (float*)d_out;

    short* ws  = (short*)d_ws;   // 40960 + 4096*1024 shorts ~= 8.1 MB scratch
    short* WvB = ws + WV_OFF;
    short* WoB = ws + WO_OFF;
    short* WfB = ws + WF_OFF;
    short* kqc = ws + KQ_OFF;

    hipLaunchKernelGGL(prep_kernel, dim3(PACK_BLOCKS + QK_BLOCKS), dim3(256), 0, stream,
                       Wk, Wv, Wq, Wo, W_filt, b_filt, x, ws);
    hipLaunchKernelGGL(tdt_main, dim3(BB * AA), dim3(256), 0, stream,
                       x, r_ij, f_ij, bo, nbr, msk,
                       WvB, WoB, WfB, kqc, out);
}

// Round 17
// 162.273 us; speedup vs baseline: 1.1897x; 1.1897x over previous
//
#include <hip/hip_runtime.h>
#include <math.h>

// Problem constants (match reference)
#define BB 8
#define AA 512
#define NBH 64
#define FF 128
#define GG 50
#define CUTOFF 5.0f

typedef __attribute__((ext_vector_type(8)))  short bf16x8;   // 8 bf16 = 4 VGPRs
typedef __attribute__((ext_vector_type(4)))  float f32x4;    // 16x16 MFMA C/D
typedef __attribute__((ext_vector_type(16))) float f32x16;   // 32x32 MFMA C/D

#define MST 136   // M_s row stride (shorts); with XOR swizzle reads/writes are conflict-light

// Packed weight sizes (bf16 elems)
#define WKV_ELEMS (4*8*64*8)   // 16384 : Wk/Wv, 32-col B-frag layout, K=128 (8 steps of 16)
#define WQO_ELEMS (8*4*64*8)   // 16384 : Wq/Wo, 16-col B-frag layout, K=128 (4 steps of 32)
#define WF_ELEMS  (4*4*64*8)   // 8192  : W_filt, 32-col layout, K=64 pad; row 50 = b_filt
#define XB_ELEMS  (BB*AA*FF)   // 524288: x pre-converted to bf16

// RNE (prep only — off critical path)
__device__ __forceinline__ short f2bf(float f) {
    union { float f; unsigned u; } v; v.f = f;
    unsigned r = v.u + 0x7fffu + ((v.u >> 16) & 1u);
    return (short)(r >> 16);
}
// fast round-half-up (2 VALU)
__device__ __forceinline__ short f2bf_fast(float f) {
    return (short)((__float_as_uint(f) + 0x8000u) >> 16);
}
// pack 2 floats -> 2 bf16 in one dword: 2 adds + 1 v_perm
__device__ __forceinline__ unsigned int pk2bf(float a, float b) {
    unsigned int ua = __float_as_uint(a) + 0x8000u;
    unsigned int ub = __float_as_uint(b) + 0x8000u;
    return __builtin_amdgcn_perm(ub, ua, 0x07060302u);
}
// Load 8 consecutive floats (8B-aligned) from global -> bf16x8 A-fragment (packed cvt)
__device__ __forceinline__ bf16x8 ld_f8_bfpk(const float* p) {
    const float2* p2 = (const float2*)p;
    float2 a = p2[0], b = p2[1], c = p2[2], d = p2[3];
    union { unsigned int u[4]; bf16x8 v; } r;
    r.u[0] = pk2bf(a.x, a.y);
    r.u[1] = pk2bf(b.x, b.y);
    r.u[2] = pk2bf(c.x, c.y);
    r.u[3] = pk2bf(d.x, d.y);
    return r.v;
}
__device__ __forceinline__ int swz(int n) { return ((n >> 3) & 3) << 3; }  // LDS k-index XOR swizzle

// Sum over the 16-lane DPP row (VALU pipe). All 16 lanes get the sum.
__device__ __forceinline__ float row16_sum(float x) {
    int t;
    t = __builtin_amdgcn_update_dpp(0, __float_as_int(x), 0x128, 0xf, 0xf, true); x += __int_as_float(t); // row_ror:8
    t = __builtin_amdgcn_update_dpp(0, __float_as_int(x), 0x124, 0xf, 0xf, true); x += __int_as_float(t); // row_ror:4
    t = __builtin_amdgcn_update_dpp(0, __float_as_int(x), 0x122, 0xf, 0xf, true); x += __int_as_float(t); // row_ror:2
    t = __builtin_amdgcn_update_dpp(0, __float_as_int(x), 0x121, 0xf, 0xf, true); x += __int_as_float(t); // row_ror:1
    return x;
}

// ---------------- prep: pack weights into MFMA B-fragment order + x -> bf16 ---------
// 32-col layout (Wk/Wv/Wf): dst[((w*S+s)*64+l)*8+j] = W[16s + (l>>5)*8 + j][32w + (l&31)]
// 16-col layout (Wq/Wo):    dst[((c*4+s)*64+l)*8+j] = W[32s + (l>>4)*8 + j][16c + (l&15)]
// Wf K-pad rows 50..63: row 50 carries b_filt (A supplies 1.0 there), 51..63 zero.
__global__ void prep_kernel(const float* __restrict__ Wk,
                            const float* __restrict__ Wv,
                            const float* __restrict__ Wq,
                            const float* __restrict__ Wo,
                            const float* __restrict__ Wf,
                            const float* __restrict__ b_filt,
                            const float* __restrict__ x,
                            short* __restrict__ ws)
{
    int gid = blockIdx.x * blockDim.x + threadIdx.x;
    if (gid < 2 * WKV_ELEMS) {
        const float* src = (gid < WKV_ELEMS) ? Wk : Wv;
        int idx = gid & (WKV_ELEMS - 1);
        int j = idx & 7, l = (idx >> 3) & 63, rest = idx >> 9;
        int s = rest & 7, w = rest >> 3;
        int k = 16 * s + ((l >> 5) << 3) + j;
        int n = 32 * w + (l & 31);
        ws[gid] = f2bf(src[k * FF + n]);
    } else if (gid < 2 * WKV_ELEMS + 2 * WQO_ELEMS) {
        int idx2 = gid - 2 * WKV_ELEMS;
        const float* src = (idx2 < WQO_ELEMS) ? Wq : Wo;
        int idx = idx2 & (WQO_ELEMS - 1);
        int j = idx & 7, l = (idx >> 3) & 63, rest = idx >> 9;
        int s = rest & 3, c = rest >> 2;
        int k = 32 * s + (l >> 4) * 8 + j;
        int n = 16 * c + (l & 15);
        ws[gid] = f2bf(src[k * FF + n]);
    } else if (gid < 2 * WKV_ELEMS + 2 * WQO_ELEMS + WF_ELEMS) {
        int idx = gid - 2 * WKV_ELEMS - 2 * WQO_ELEMS;
        int j = idx & 7, l = (idx >> 3) & 63, rest = idx >> 9;
        int s = rest & 3, w = rest >> 2;
        int k = 16 * s + ((l >> 5) << 3) + j;
        int n = 32 * w + (l & 31);
        float v = (k < GG) ? Wf[k * FF + n] : (k == GG ? b_filt[n] : 0.0f);
        ws[gid] = f2bf(v);
    } else {
        int idx = gid - 2 * WKV_ELEMS - 2 * WQO_ELEMS - WF_ELEMS;
        ws[gid] = f2bf(x[idx]);            // xB: straight layout, (b*AA+a)*FF + col
    }
}

// ---------------- main: one block per atom, 4 waves, 2 barriers ----------------
// Wave w owns cols [32w, 32w+32) == heads {2w, 2w+1}, all 64 neighbors.
// 32x32x16 layouts: A[m=lane&31][k=(lane>>5)*8+j]  B[k][n=lane&31]
//                   D: col=lane&31, row=(reg&3)+8*(reg>>2)+4*(lane>>5)
// Phase 2: k-MFMA and v-MFMA interleaved per s-step — each M_s fragment is
// TRANSIENT (loaded once, feeds both, dies). Softmax is max-free (|score| small
// by construction; masked -> e=0) with one final 1/sum.
// launch_bounds min-waves=4 (128-reg cap): 6 forced catastrophic spill (R6:
// WRITE_SIZE 405 MB). kq-style score precompute regressed on TOTALS three ways
// (R8/R10 in-main serial; R14 VALU prep +55us; R15/R16 prep+launch overhead
// exceeds the 5us main saving) — this structure is the measured total optimum.
__global__ __launch_bounds__(256, 4)
void tdt_main(const float* __restrict__ x,
              const float* __restrict__ r_ij,
              const float* __restrict__ f_ij,
              const float* __restrict__ bo,
              const int*   __restrict__ neighbors,
              const int*   __restrict__ nmask,
              const short* __restrict__ WkB,
              const short* __restrict__ WvB,
              const short* __restrict__ WqB,
              const short* __restrict__ WoB,
              const short* __restrict__ WfB,
              const short* __restrict__ xB,
              float* __restrict__ out)
{
    const int ba   = blockIdx.x;          // 0..4095
    const int b    = ba >> 9;
    const int tid  = threadIdx.x;
    const int lane = tid & 63;
    const int w    = tid >> 6;            // wave 0..3
    const int l15  = lane & 15;
    const int quad = lane >> 4;
    const int l31  = lane & 31;
    const int khalf = (lane >> 5) << 3;   // 0 or 8
    const int w5_4  = (lane >> 5) * 4;

    __shared__ short M_s[NBH * MST];      // modulated messages, swizzled (17.4 KB)
    __shared__ short msg_bf[FF];

    const float* xrow = x + (size_t)ba * FF;                       // residual (fp32)
    const unsigned short* xbu = (const unsigned short*)xB + (size_t)b * AA * FF;
    const size_t bao = (size_t)ba;

    // per-lane neighbor metadata in REGISTERS (no LDS, no barrier):
    int   nbr_reg = neighbors[bao * NBH + lane];
    float C_reg;
    {
        float r = r_ij[bao * NBH + lane];
        float c = 0.5f * (__cosf((float)M_PI * r * (1.0f / CUTOFF)) + 1.0f);
        C_reg = (r < CUTOFF) ? c : 0.0f;
    }
    unsigned long long mask64 = __ballot(nmask[bao * NBH + lane] != 0);

    // ---------------- phase 1a: q via 16x16x32 MFMA (broadcast-A from xB) -----------
    // Only qvm = 0.25 * q[32w + (lane&31)] stays live downstream.
    float qvm;
    {
        const short* xbrow = &xB[(size_t)ba * FF];
        bf16x8 xa[4];
#pragma unroll
        for (int s = 0; s < 4; ++s)
            xa[s] = *(const bf16x8*)&xbrow[32 * s + quad * 8];     // raw 16B, no cvt
        float qv0, qv1;
#pragma unroll
        for (int ct = 0; ct < 2; ++ct) {
            int cg = 2 * w + ct;
            f32x4 z = {0.f, 0.f, 0.f, 0.f};
#pragma unroll
            for (int s = 0; s < 4; ++s) {
                bf16x8 bq = *(const bf16x8*)&WqB[((cg * 4 + s) * 64 + lane) * 8];
                z = __builtin_amdgcn_mfma_f32_16x16x32_bf16(xa[s], bq, z, 0, 0, 0);
            }
            if (ct == 0) qv0 = z[0]; else qv1 = z[0];
        }
        qvm = (((lane >> 4) & 1) ? qv1 : qv0) * 0.25f;             // fold 1/sqrt(DH)
    }

    // ---------------- phase 1b: filter 32x32x16 MFMA (A from global f_ij), mt-split -
    {
        const float* fm0 = f_ij + bao * (size_t)(NBH * GG) + (size_t)l31 * GG;
        int c = 32 * w + l31;
#pragma unroll
        for (int mt = 0; mt < 2; ++mt) {
            f32x16 wacc;
#pragma unroll
            for (int r = 0; r < 16; ++r) wacc[r] = 0.0f;
            const float* fm = fm0 + mt * 32 * GG;
#pragma unroll
            for (int s = 0; s < 4; ++s) {
                bf16x8 bfw = *(const bf16x8*)&WfB[((w * 4 + s) * 64 + lane) * 8];
                bf16x8 fa;
                if (s < 3) {
                    fa = ld_f8_bfpk(fm + 16 * s + khalf);
                } else {
                    // k = 48 + khalf + j; k<50 real data, k==50 bias row (A=1.0)
#pragma unroll
                    for (int jj = 0; jj < 8; ++jj) fa[jj] = 0;
                    if (lane < 32) {
                        fa[0] = f2bf_fast(fm[48]);
                        fa[1] = f2bf_fast(fm[49]);
                        fa[2] = (short)0x3F80;   // 1.0bf16 -> adds b_filt row
                    }
                }
                wacc = __builtin_amdgcn_mfma_f32_32x32x16_bf16(fa, bfw, wacc, 0, 0, 0);
            }
            // modulate + gather (bf16 x) + write M_s
#pragma unroll
            for (int r = 0; r < 16; ++r) {
                int   n   = 32 * mt + (r & 3) + 8 * (r >> 2) + w5_4;
                int   nbn = __shfl(nbr_reg, n, 64);
                float cn  = __shfl(C_reg, n, 64);
                float xv  = __uint_as_float((unsigned)xbu[(size_t)nbn * FF + c] << 16);
                M_s[n * MST + (c ^ swz(n))] = f2bf_fast(wacc[r] * cn * xv);
            }
        }
    }
    __syncthreads();   // M_s ready

    // ---------------- phase 2: interleaved k/v MFMA + max-free softmax + msg --------
    float sum = 0.0f, acc = 0.0f;
#pragma unroll
    for (int mt = 0; mt < 2; ++mt) {
        int m = 32 * mt + l31;
        f32x16 kacc, vacc;
#pragma unroll
        for (int r = 0; r < 16; ++r) { kacc[r] = 0.0f; vacc[r] = 0.0f; }
#pragma unroll
        for (int s = 0; s < 8; ++s) {
            bf16x8 ma = *(const bf16x8*)&M_s[m * MST + ((16 * s + khalf) ^ swz(m))];
            bf16x8 bk = *(const bf16x8*)&WkB[((w * 8 + s) * 64 + lane) * 8];
            bf16x8 bv = *(const bf16x8*)&WvB[((w * 8 + s) * 64 + lane) * 8];
            kacc = __builtin_amdgcn_mfma_f32_32x32x16_bf16(ma, bk, kacc, 0, 0, 0);
            vacc = __builtin_amdgcn_mfma_f32_32x32x16_bf16(ma, bv, vacc, 0, 0, 0);
        }
#pragma unroll
        for (int r = 0; r < 16; ++r) {
            float sr = row16_sum(kacc[r] * qvm);       // score for (n, lane's head)
            int   n  = 32 * mt + (r & 3) + 8 * (r >> 2) + w5_4;
            float e  = ((mask64 >> n) & 1ull) ? __expf(sr) : 0.0f;
            sum += e;
            acc  = fmaf(e, vacc[r], acc);
        }
    }
    sum += __shfl_xor(sum, 32, 64);                    // other 32 neighbors
    acc += __shfl_xor(acc, 32, 64);
    if (lane < 32) msg_bf[32 * w + l31] = f2bf_fast(acc / sum);
    __syncthreads();   // msg_bf ready

    // ---------------- phase 3: out = msg.Wo + x + bo (16x16x32, broadcast-A) --------
    {
        bf16x8 mga[4];
#pragma unroll
        for (int s = 0; s < 4; ++s)
            mga[s] = *(const bf16x8*)&msg_bf[s * 32 + quad * 8];
#pragma unroll
        for (int ct = 0; ct < 2; ++ct) {
            int cg = 2 * w + ct;
            f32x4 z = {0.f, 0.f, 0.f, 0.f};
#pragma unroll
            for (int s = 0; s < 4; ++s) {
                bf16x8 bw = *(const bf16x8*)&WoB[((cg * 4 + s) * 64 + lane) * 8];
                z = __builtin_amdgcn_mfma_f32_16x16x32_bf16(mga[s], bw, z, 0, 0, 0);
            }
            if (quad == 0) {
                int col = cg * 16 + l15;
                out[bao * FF + col] = z[0] + xrow[col] + bo[col];
            }
        }
    }
}

extern "C" void kernel_launch(void* const* d_in, const int* in_sizes, int n_in,
                              void* d_out, int out_size, void* d_ws, size_t ws_size,
                              hipStream_t stream) {
    // 0:e 1:x 2:t 3:r_ij 4:f_ij 5:W_filt 6:b_filt 7:Wq 8:Wk 9:Wv 10:Wo 11:bo
    // 12:neighbors 13:neighbor_mask (bool -> int32)
    const float* x      = (const float*)d_in[1];
    const float* r_ij   = (const float*)d_in[3];
    const float* f_ij   = (const float*)d_in[4];
    const float* W_filt = (const float*)d_in[5];
    const float* b_filt = (const float*)d_in[6];
    const float* Wq     = (const float*)d_in[7];
    const float* Wk     = (const float*)d_in[8];
    const float* Wv     = (const float*)d_in[9];
    const float* Wo     = (const float*)d_in[10];
    const float* bo     = (const float*)d_in[11];
    const int*   nbr    = (const int*)d_in[12];
    const int*   msk    = (const int*)d_in[13];
    float* out = (float*)d_out;

    short* ws  = (short*)d_ws;   // 73728 + 524288 bf16 = 1.17 MB scratch
    short* WkB = ws;
    short* WvB = ws + WKV_ELEMS;
    short* WqB = ws + 2 * WKV_ELEMS;
    short* WoB = ws + 2 * WKV_ELEMS + WQO_ELEMS;
    short* WfB = ws + 2 * WKV_ELEMS + 2 * WQO_ELEMS;
    short* xB  = ws + 2 * WKV_ELEMS + 2 * WQO_ELEMS + WF_ELEMS;

    int prep_total = 2 * WKV_ELEMS + 2 * WQO_ELEMS + WF_ELEMS + XB_ELEMS; // 598016 = 2336*256
    hipLaunchKernelGGL(prep_kernel, dim3(prep_total / 256), dim3(256), 0, stream,
                       Wk, Wv, Wq, Wo, W_filt, b_filt, x, ws);
    hipLaunchKernelGGL(tdt_main, dim3(BB * AA), dim3(256), 0, stream,
                       x, r_ij, f_ij, bo, nbr, msk,
                       WkB, WvB, WqB, WoB, WfB, xB, out);
}